// Round 8
// baseline (329.399 us; speedup 1.0000x reference)
//
#include <hip/hip_runtime.h>

// Problem constants (from reference)
#define BS 65536
#define NE 512
#define D  768
#define D4 192                     // D / 4 (float4 per row); 192 = 3 * 64 lanes
#define ROWS_PER_WAVE 2
#define WAVES_PER_BLOCK 4
#define ROWS_PER_BLOCK 8           // 4 waves * 2 rows
#define NBLK (BS / ROWS_PER_BLOCK) // 8192 blocks
#define NPART (NBLK * WAVES_PER_BLOCK) // 32768 float partials = 128 KB ws

// Native clang vector type — required by nontemporal load/store builtins
// (HIP's float4 struct wrapper is rejected). Supports .x/.y/.z/.w access.
typedef float floatx4 __attribute__((ext_vector_type(4)));

#define ACCV(Q, X)                                                         \
    { floatx4 d_ = (Q) - (X);                                              \
      acc += d_.x * d_.x + d_.y * d_.y + d_.z * d_.z + d_.w * d_.w; }

// SINGLE-VARIABLE EXPERIMENT vs R4: identical fused structure, but the 6
// input loads are NONTEMPORAL (no L2/L3 allocate). R7 confounded {phase
// split} x {NT input loads}; this isolates the NT-load variable while
// keeping the fused kernel's advantages (one launch, one categories read,
// one codebook gather pass).
__global__ __launch_bounds__(256) void vq_main(
    const float4* __restrict__ inputs,
    const int*    __restrict__ categories,
    const float4* __restrict__ codebook,
    float4*       __restrict__ out,
    float*        __restrict__ partials)
{
    const int lane = threadIdx.x & 63;
    const int wave = threadIdx.x >> 6;
    const int wid  = blockIdx.x * WAVES_PER_BLOCK + wave;
    const int row0 = blockIdx.x * ROWS_PER_BLOCK + wave * ROWS_PER_WAVE;
    // row0 is wave-uniform; readfirstlane lets the compiler emit scalar loads
    const int r0 = __builtin_amdgcn_readfirstlane(row0);

    // 2 contiguous wave-uniform category reads -> one s_load_dwordx2
    const int c0 = categories[r0];
    const int c1 = categories[r0 + 1];

    // 6 NONTEMPORAL input loads — streaming, no cache allocate: don't evict
    // the L2-resident codebook or the dirty `out` lines parked in L3.
    const floatx4* ip = (const floatx4*)inputs + (size_t)row0 * D4 + lane;
    const floatx4 x00 = __builtin_nontemporal_load(ip);
    const floatx4 x01 = __builtin_nontemporal_load(ip + 64);
    const floatx4 x02 = __builtin_nontemporal_load(ip + 128);
    const floatx4 x10 = __builtin_nontemporal_load(ip + 192);
    const floatx4 x11 = __builtin_nontemporal_load(ip + 256);
    const floatx4 x12 = __builtin_nontemporal_load(ip + 320);

    // 6 gather loads (plain — codebook is 1.5 MB, L2-resident on every XCD)
    const floatx4* cb0 = (const floatx4*)codebook + (size_t)c0 * D4 + lane;
    const floatx4* cb1 = (const floatx4*)codebook + (size_t)c1 * D4 + lane;
    const floatx4 q00 = cb0[0], q01 = cb0[64], q02 = cb0[128];
    const floatx4 q10 = cb1[0], q11 = cb1[64], q12 = cb1[128];

    // quantized_st forward value == quantized: out is just the gathered rows.
    // Plain stores (NT stores measured harmful in R2-R4).
    floatx4* op = (floatx4*)out + (size_t)row0 * D4 + lane;
    op[0]   = q00;  op[64]  = q01;  op[128] = q02;
    op[192] = q10;  op[256] = q11;  op[320] = q12;

    float acc = 0.0f;
    ACCV(q00, x00) ACCV(q01, x01) ACCV(q02, x02)
    ACCV(q10, x10) ACCV(q11, x11) ACCV(q12, x12)

    // Wave (64-lane) shuffle reduction; one partial per wave, no barrier.
    #pragma unroll
    for (int off = 32; off > 0; off >>= 1)
        acc += __shfl_down(acc, off, 64);

    if (lane == 0)
        partials[wid] = acc;
}

// Finalize: reduce 32768 per-wave partials -> loss scalar at out[BS*D].
// loss = (CODEBOOK_COST + COMMITMENT_COST) * mean(diff^2) = 1.25 * sum / (BS*D)
__global__ __launch_bounds__(1024) void vq_finalize(
    const float* __restrict__ partials,
    float*       __restrict__ loss_out)
{
    const int t = threadIdx.x;
    double s = 0.0;
    #pragma unroll
    for (int k = 0; k < NPART / 1024; ++k)     // 32 coalesced loads/thread
        s += (double)partials[t + (k << 10)];

    #pragma unroll
    for (int off = 32; off > 0; off >>= 1)
        s += __shfl_down(s, off, 64);

    __shared__ double wsum[16];
    const int lane = t & 63, wave = t >> 6;
    if (lane == 0) wsum[wave] = s;
    __syncthreads();

    if (t == 0) {
        double tot = 0.0;
        #pragma unroll
        for (int w = 0; w < 16; ++w) tot += wsum[w];
        *loss_out = (float)(tot * (1.25 / ((double)BS * (double)D)));
    }
}

extern "C" void kernel_launch(void* const* d_in, const int* in_sizes, int n_in,
                              void* d_out, int out_size, void* d_ws, size_t ws_size,
                              hipStream_t stream) {
    const float4* inputs     = (const float4*)d_in[0];
    const int*    categories = (const int*)  d_in[1];  // jnp.int64 canonicalizes to int32
    const float4* codebook   = (const float4*)d_in[2];
    float*        out        = (float*)d_out;
    float*        partials   = (float*)d_ws;           // 32768 * 4 B = 128 KB of workspace

    // Every partial slot is overwritten by vq_main before vq_finalize reads it,
    // so no memset of the poisoned workspace is needed.
    vq_main<<<NBLK, 256, 0, stream>>>(inputs, categories, codebook,
                                      (float4*)out, partials);
    vq_finalize<<<1, 1024, 0, stream>>>(partials, out + (size_t)BS * D);
}

// Round 9
// 328.499 us; speedup vs baseline: 1.0027x; 1.0027x over previous
//
#include <hip/hip_runtime.h>

// Problem constants (from reference)
#define BS 65536
#define NE 512
#define D  768
#define D4 192                     // D / 4 (float4 per row); 192 = 3 * 64 lanes
#define ROWS_PER_WAVE 2
#define WAVES_PER_BLOCK 4
#define ROWS_PER_BLOCK 8           // 4 waves * 2 rows
#define NBLK (BS / ROWS_PER_BLOCK) // 8192 blocks
#define NPART (NBLK * WAVES_PER_BLOCK) // 32768 float partials = 128 KB ws

// Native clang vector type — required by nontemporal load/store builtins
// (HIP's float4 struct wrapper is rejected). Supports .x/.y/.z/.w access.
typedef float floatx4 __attribute__((ext_vector_type(4)));

#define ACCV(Q, X)                                                         \
    { floatx4 d_ = (Q) - (X);                                              \
      acc += d_.x * d_.x + d_.y * d_.y + d_.z * d_.z + d_.w * d_.w; }

// SINGLE-VARIABLE EXPERIMENT vs R8: identical kernel, but the 6 out stores
// are NONTEMPORAL. R2-era "NT stores harmful" was confounded (3 variables).
// Gain mechanism: skip L2 write-allocate on the 201 MB out stream -> L2
// stays codebook-only, no 201 MB of fill/evict churn.
__global__ __launch_bounds__(256) void vq_main(
    const float4* __restrict__ inputs,
    const int*    __restrict__ categories,
    const float4* __restrict__ codebook,
    float4*       __restrict__ out,
    float*        __restrict__ partials)
{
    const int lane = threadIdx.x & 63;
    const int wave = threadIdx.x >> 6;
    const int wid  = blockIdx.x * WAVES_PER_BLOCK + wave;
    const int row0 = blockIdx.x * ROWS_PER_BLOCK + wave * ROWS_PER_WAVE;
    // row0 is wave-uniform; readfirstlane lets the compiler emit scalar loads
    const int r0 = __builtin_amdgcn_readfirstlane(row0);

    // 2 contiguous wave-uniform category reads -> one s_load_dwordx2
    const int c0 = categories[r0];
    const int c1 = categories[r0 + 1];

    // 6 NONTEMPORAL input loads — streaming, no cache allocate: don't evict
    // the L2-resident codebook or the dirty `out` lines parked in L3.
    const floatx4* ip = (const floatx4*)inputs + (size_t)row0 * D4 + lane;
    const floatx4 x00 = __builtin_nontemporal_load(ip);
    const floatx4 x01 = __builtin_nontemporal_load(ip + 64);
    const floatx4 x02 = __builtin_nontemporal_load(ip + 128);
    const floatx4 x10 = __builtin_nontemporal_load(ip + 192);
    const floatx4 x11 = __builtin_nontemporal_load(ip + 256);
    const floatx4 x12 = __builtin_nontemporal_load(ip + 320);

    // 6 gather loads (plain — codebook is 1.5 MB, L2-resident on every XCD)
    const floatx4* cb0 = (const floatx4*)codebook + (size_t)c0 * D4 + lane;
    const floatx4* cb1 = (const floatx4*)codebook + (size_t)c1 * D4 + lane;
    const floatx4 q00 = cb0[0], q01 = cb0[64], q02 = cb0[128];
    const floatx4 q10 = cb1[0], q11 = cb1[64], q12 = cb1[128];

    // quantized_st forward value == quantized: out is just the gathered rows.
    // NT stores: no L2 write-allocate for the write-once 201 MB stream.
    floatx4* op = (floatx4*)out + (size_t)row0 * D4 + lane;
    __builtin_nontemporal_store(q00, op);
    __builtin_nontemporal_store(q01, op + 64);
    __builtin_nontemporal_store(q02, op + 128);
    __builtin_nontemporal_store(q10, op + 192);
    __builtin_nontemporal_store(q11, op + 256);
    __builtin_nontemporal_store(q12, op + 320);

    float acc = 0.0f;
    ACCV(q00, x00) ACCV(q01, x01) ACCV(q02, x02)
    ACCV(q10, x10) ACCV(q11, x11) ACCV(q12, x12)

    // Wave (64-lane) shuffle reduction; one partial per wave, no barrier.
    #pragma unroll
    for (int off = 32; off > 0; off >>= 1)
        acc += __shfl_down(acc, off, 64);

    if (lane == 0)
        partials[wid] = acc;
}

// Finalize: reduce 32768 per-wave partials -> loss scalar at out[BS*D].
// loss = (CODEBOOK_COST + COMMITMENT_COST) * mean(diff^2) = 1.25 * sum / (BS*D)
__global__ __launch_bounds__(1024) void vq_finalize(
    const float* __restrict__ partials,
    float*       __restrict__ loss_out)
{
    const int t = threadIdx.x;
    double s = 0.0;
    #pragma unroll
    for (int k = 0; k < NPART / 1024; ++k)     // 32 coalesced loads/thread
        s += (double)partials[t + (k << 10)];

    #pragma unroll
    for (int off = 32; off > 0; off >>= 1)
        s += __shfl_down(s, off, 64);

    __shared__ double wsum[16];
    const int lane = t & 63, wave = t >> 6;
    if (lane == 0) wsum[wave] = s;
    __syncthreads();

    if (t == 0) {
        double tot = 0.0;
        #pragma unroll
        for (int w = 0; w < 16; ++w) tot += wsum[w];
        *loss_out = (float)(tot * (1.25 / ((double)BS * (double)D)));
    }
}

extern "C" void kernel_launch(void* const* d_in, const int* in_sizes, int n_in,
                              void* d_out, int out_size, void* d_ws, size_t ws_size,
                              hipStream_t stream) {
    const float4* inputs     = (const float4*)d_in[0];
    const int*    categories = (const int*)  d_in[1];  // jnp.int64 canonicalizes to int32
    const float4* codebook   = (const float4*)d_in[2];
    float*        out        = (float*)d_out;
    float*        partials   = (float*)d_ws;           // 32768 * 4 B = 128 KB of workspace

    // Every partial slot is overwritten by vq_main before vq_finalize reads it,
    // so no memset of the poisoned workspace is needed.
    vq_main<<<NBLK, 256, 0, stream>>>(inputs, categories, codebook,
                                      (float4*)out, partials);
    vq_finalize<<<1, 1024, 0, stream>>>(partials, out + (size_t)BS * D);
}